// Round 9
// baseline (735.389 us; speedup 1.0000x reference)
//
#include <hip/hip_runtime.h>
#include <hip/hip_fp16.h>

#define NN 100000
#define NE 1600000
#define NBKT 196              // buckets of 512 cols: 99999>>9 = 195
#define BSH 9
#define BCAP 9216             // mean 8163 + 11.7 sigma
#define NCOL (NBKT * 512)     // 100352 = 98 * 1024 (scan-friendly)
#define EPB_A 4096

typedef __half half_t;
using f16x8 = __attribute__((ext_vector_type(8))) _Float16;
using f32x4 = __attribute__((ext_vector_type(4))) float;

// ---------------- helpers ----------------

__device__ inline float4 load4(const float* p) {
    return *reinterpret_cast<const float4*>(p);
}
__device__ inline float4 load4(const half_t* p) {
    uint2 u = *reinterpret_cast<const uint2*>(p);
    __half2 a = *reinterpret_cast<__half2*>(&u.x);
    __half2 b = *reinterpret_cast<__half2*>(&u.y);
    float2 fa = __half22float2(a), fb = __half22float2(b);
    return make_float4(fa.x, fa.y, fb.x, fb.y);
}
__device__ inline void store_half4(half_t* p, float4 v) {
    __half2 a = __floats2half2_rn(v.x, v.y);
    __half2 b = __floats2half2_rn(v.z, v.w);
    uint2 u;
    u.x = *reinterpret_cast<unsigned*>(&a);
    u.y = *reinterpret_cast<unsigned*>(&b);
    *reinterpret_cast<uint2*>(p) = u;
}

// ---------------- setup: two-level bucket CSR build ----------------

__global__ void f32_to_f16(const float* __restrict__ in, half_t* __restrict__ out, int nquad) {
    int i = blockIdx.x * blockDim.x + threadIdx.x;
    if (i < nquad) store_half4(out + i * 4, load4(in + i * 4));
}

// passA: block-local counting sort by coarse bucket, sequential flush.
// packed = (col&511)<<17 | row   (row < 2^17)
__global__ __launch_bounds__(256) void passA_bucket(
    const int* __restrict__ row, const int* __restrict__ col, const float* __restrict__ w,
    unsigned* __restrict__ gcur, int2* __restrict__ gbkt, int E)
{
    __shared__ unsigned cnt[256];
    __shared__ unsigned lofs[256];
    __shared__ unsigned lcur[256];
    __shared__ unsigned gb[256];
    __shared__ int2 arena[EPB_A];
    __shared__ unsigned short abkt[EPB_A];
    int t = threadIdx.x;
    int base = blockIdx.x * EPB_A;
    int nloc = min(EPB_A, E - base);
    cnt[t] = 0; lcur[t] = 0;
    __syncthreads();
    for (int i = t; i < nloc; i += 256)
        atomicAdd(&cnt[col[base + i] >> BSH], 1u);
    __syncthreads();
    unsigned v = cnt[t];
    lofs[t] = v; __syncthreads();
    for (int d = 1; d < 256; d <<= 1) {
        unsigned u = (t >= d) ? lofs[t - d] : 0u;
        __syncthreads();
        lofs[t] += u;
        __syncthreads();
    }
    unsigned excl = lofs[t] - v;
    __syncthreads();
    lofs[t] = excl;
    __syncthreads();
    if (t < NBKT && cnt[t] > 0) gb[t] = atomicAdd(&gcur[t], cnt[t]);
    for (int i = t; i < nloc; i += 256) {
        int e = base + i;
        int c = col[e];
        int b = c >> BSH;
        unsigned p = lofs[b] + atomicAdd(&lcur[b], 1u);
        unsigned packed = ((unsigned)(c & 511) << 17) | (unsigned)row[e];
        arena[p] = make_int2((int)packed, __float_as_int(w[e]));
        abkt[p] = (unsigned short)b;
    }
    __syncthreads();
    for (int i = t; i < nloc; i += 256) {
        int b = abkt[i];
        unsigned j = i - lofs[b];
        gbkt[(size_t)b * BCAP + gb[b] + j] = arena[i];
    }
}

// passB: per-bucket 512-col histogram + weighted degree, sequential writes
__global__ __launch_bounds__(256) void passB_hist(
    const int2* __restrict__ gbkt, const unsigned* __restrict__ gcur,
    unsigned* __restrict__ cnt, float* __restrict__ deg)
{
    __shared__ unsigned c512[512];
    __shared__ float d512[512];
    int t = threadIdx.x;
    int b = blockIdx.x;
    for (int i = t; i < 512; i += 256) { c512[i] = 0; d512[i] = 0.f; }
    __syncthreads();
    unsigned sz = min(gcur[b], (unsigned)BCAP);
    const int2* src = gbkt + (size_t)b * BCAP;
    for (unsigned i = t; i < sz; i += 256) {
        int2 v = src[i];
        unsigned colw = ((unsigned)v.x) >> 17;
        atomicAdd(&c512[colw], 1u);
        atomicAdd(&d512[colw], __int_as_float(v.y));
    }
    __syncthreads();
    for (int i = t; i < 512; i += 256) {
        cnt[b * 512 + i] = c512[i];
        deg[b * 512 + i] = d512[i];
    }
}

__global__ void dinv_kernel(const float* __restrict__ deg, float* __restrict__ dinv, int n) {
    int i = blockIdx.x * blockDim.x + threadIdx.x;
    if (i < n) {
        float d = deg[i];
        dinv[i] = d > 0.f ? rsqrtf(d) : 0.f;
    }
}

__global__ void scan_phase1(const unsigned* __restrict__ cnt, unsigned* __restrict__ bsum, int n) {
    __shared__ unsigned sh[256];
    int t = threadIdx.x;
    int base = blockIdx.x * 1024 + t * 4;
    unsigned s = 0;
#pragma unroll
    for (int j = 0; j < 4; j++) { int i = base + j; if (i < n) s += cnt[i]; }
    sh[t] = s; __syncthreads();
    for (int d = 128; d > 0; d >>= 1) {
        if (t < d) sh[t] += sh[t + d];
        __syncthreads();
    }
    if (t == 0) bsum[blockIdx.x] = sh[0];
}

__global__ void scan_phase2(const unsigned* __restrict__ bsum, unsigned* __restrict__ bbase, int nb) {
    __shared__ unsigned sh[128];
    int t = threadIdx.x;
    unsigned v = (t < nb) ? bsum[t] : 0u;
    sh[t] = v; __syncthreads();
    for (int d = 1; d < 128; d <<= 1) {
        unsigned u = (t >= d) ? sh[t - d] : 0u;
        __syncthreads();
        sh[t] += u;
        __syncthreads();
    }
    if (t < nb) bbase[t] = sh[t] - v;   // exclusive
}

__global__ void scan_phase3(const unsigned* __restrict__ cnt, const unsigned* __restrict__ bbase,
                            unsigned* __restrict__ offsets, int n) {
    __shared__ unsigned sh[256];
    int t = threadIdx.x;
    int base = blockIdx.x * 1024 + t * 4;
    unsigned c[4]; unsigned s = 0;
#pragma unroll
    for (int j = 0; j < 4; j++) { int i = base + j; c[j] = (i < n) ? cnt[i] : 0u; s += c[j]; }
    sh[t] = s; __syncthreads();
    for (int d = 1; d < 256; d <<= 1) {
        unsigned u = (t >= d) ? sh[t - d] : 0u;
        __syncthreads();
        sh[t] += u;
        __syncthreads();
    }
    unsigned o = bbase[blockIdx.x] + sh[t] - s;
#pragma unroll
    for (int j = 0; j < 4; j++) {
        int i = base + j;
        if (i < n) { offsets[i] = o; o += c[j]; }
    }
}

// passC: per-bucket placement into final CSR; scatter window ~65KB (L2-resident).
__global__ __launch_bounds__(256) void passC_place(
    const int2* __restrict__ gbkt, const unsigned* __restrict__ gcur,
    const unsigned* __restrict__ offsets, const float* __restrict__ dinv,
    int2* __restrict__ ent)
{
    __shared__ unsigned lcur[512];
    int t = threadIdx.x;
    int b = blockIdx.x;
    for (int i = t; i < 512; i += 256) lcur[i] = 0;
    __syncthreads();
    unsigned sz = min(gcur[b], (unsigned)BCAP);
    const int2* src = gbkt + (size_t)b * BCAP;
    for (unsigned i = t; i < sz; i += 256) {
        int2 v = src[i];
        unsigned colw = ((unsigned)v.x) >> 17;
        int r = v.x & 0x1FFFF;
        int c = (b << BSH) | (int)colw;
        unsigned pos = offsets[c] + atomicAdd(&lcur[colw], 1u);
        float wv = __int_as_float(v.y) * dinv[r];
        ent[pos] = make_int2(r, __float_as_int(wv));
    }
}

// ---------------- SpMM dim-32, 8 lanes/node, 8-edge MLP batches ----------------
// src/pout f16: row = 64B; lane covers 4 halfs (8B).

__global__ __launch_bounds__(256) void spmm32_kernel(
    const half_t* __restrict__ src, half_t* __restrict__ pout,
    const int2* __restrict__ ent, const unsigned* __restrict__ offs,
    const unsigned* __restrict__ cnt, const float* __restrict__ dinv, int n)
{
    int node = blockIdx.x * 32 + (threadIdx.x >> 3);
    int f = (threadIdx.x & 7) * 4;
    if (node >= n) return;
    unsigned e = offs[node];
    unsigned end = e + cnt[node];
    float dv = dinv[node];
    float acc[4] = {};
    for (; e + 8 <= end; e += 8) {
        int2 en[8];
#pragma unroll
        for (int j = 0; j < 8; ++j) en[j] = ent[e + j];
        uint2 raw[8];
#pragma unroll
        for (int j = 0; j < 8; ++j)
            raw[j] = *reinterpret_cast<const uint2*>(src + (size_t)en[j].x * 32 + f);
#pragma unroll
        for (int j = 0; j < 8; ++j) {
            float w = __int_as_float(en[j].y);
            __half2* h2 = reinterpret_cast<__half2*>(&raw[j]);
            float2 v0 = __half22float2(h2[0]), v1 = __half22float2(h2[1]);
            acc[0] += w * v0.x; acc[1] += w * v0.y;
            acc[2] += w * v1.x; acc[3] += w * v1.y;
        }
    }
    for (; e < end; ++e) {
        int2 en = ent[e];
        float w = __int_as_float(en.y);
        uint2 raw = *reinterpret_cast<const uint2*>(src + (size_t)en.x * 32 + f);
        __half2* h2 = reinterpret_cast<__half2*>(&raw);
        float2 v0 = __half22float2(h2[0]), v1 = __half22float2(h2[1]);
        acc[0] += w * v0.x; acc[1] += w * v0.y;
        acc[2] += w * v1.x; acc[3] += w * v1.y;
    }
    uint2 o;
    __half2 h;
    h = __floats2half2_rn(acc[0] * dv, acc[1] * dv); o.x = *reinterpret_cast<unsigned*>(&h);
    h = __floats2half2_rn(acc[2] * dv, acc[3] * dv); o.y = *reinterpret_cast<unsigned*>(&h);
    *reinterpret_cast<uint2*>(pout + (size_t)node * 32 + f) = o;
}

// ---------------- SpMM dim-64, 8 lanes/node, 16B loads, 8-edge MLP batches ----------------

__global__ __launch_bounds__(256) void spmm64_kernel(
    const half_t* __restrict__ src, half_t* __restrict__ pout,
    const int2* __restrict__ ent, const unsigned* __restrict__ offs,
    const unsigned* __restrict__ cnt, const float* __restrict__ dinv, int n)
{
    int node = blockIdx.x * 32 + (threadIdx.x >> 3);
    int f = (threadIdx.x & 7) * 8;   // 8 halfs = 16B per lane
    if (node >= n) return;
    unsigned e = offs[node];
    unsigned end = e + cnt[node];
    float dv = dinv[node];
    float acc[8] = {};
    for (; e + 8 <= end; e += 8) {
        int2 en[8];
#pragma unroll
        for (int j = 0; j < 8; ++j) en[j] = ent[e + j];
        uint4 raw[8];
#pragma unroll
        for (int j = 0; j < 8; ++j)
            raw[j] = *reinterpret_cast<const uint4*>(src + (size_t)en[j].x * 64 + f);
#pragma unroll
        for (int j = 0; j < 8; ++j) {
            float w = __int_as_float(en[j].y);
            __half2* h2 = reinterpret_cast<__half2*>(&raw[j]);
#pragma unroll
            for (int q = 0; q < 4; ++q) {
                float2 v = __half22float2(h2[q]);
                acc[2 * q]     += w * v.x;
                acc[2 * q + 1] += w * v.y;
            }
        }
    }
    for (; e < end; ++e) {
        int2 en = ent[e];
        float w = __int_as_float(en.y);
        uint4 raw = *reinterpret_cast<const uint4*>(src + (size_t)en.x * 64 + f);
        __half2* h2 = reinterpret_cast<__half2*>(&raw);
#pragma unroll
        for (int q = 0; q < 4; ++q) {
            float2 v = __half22float2(h2[q]);
            acc[2 * q]     += w * v.x;
            acc[2 * q + 1] += w * v.y;
        }
    }
    uint4 o;
    __half2 h;
    h = __floats2half2_rn(acc[0] * dv, acc[1] * dv); o.x = *reinterpret_cast<unsigned*>(&h);
    h = __floats2half2_rn(acc[2] * dv, acc[3] * dv); o.y = *reinterpret_cast<unsigned*>(&h);
    h = __floats2half2_rn(acc[4] * dv, acc[5] * dv); o.z = *reinterpret_cast<unsigned*>(&h);
    h = __floats2half2_rn(acc[6] * dv, acc[7] * dv); o.w = *reinterpret_cast<unsigned*>(&h);
    *reinterpret_cast<uint4*>(pout + (size_t)node * 64 + f) = o;
}

// ---------------- fused 4-source matmul via MFMA f16 ----------------

template <int IN, int MODE>
__global__ __launch_bounds__(256) void fused4_mfma(
    const half_t* __restrict__ A0, const half_t* __restrict__ P1,
    const half_t* __restrict__ P2, const half_t* __restrict__ P3,
    const float* __restrict__ W, const float* __restrict__ bias,
    half_t* __restrict__ hdst, float* __restrict__ fdst, int n)
{
    constexpr int KK  = IN / 32;
    constexpr int WTS = IN + 8;
    __shared__ _Float16 Wt[64][WTS];
    int t = threadIdx.x;
    int w = t >> 6, l = t & 63;
    int nodeBase = blockIdx.x * 64;
    int rowTop = nodeBase + w * 16;

    f32x4 acc[4];
#pragma unroll
    for (int ct = 0; ct < 4; ++ct) acc[ct] = (f32x4){0.f, 0.f, 0.f, 0.f};

    int row = rowTop + (l & 15);
    if (row >= n) row = n - 1;
    const int khome = (l >> 4) * 8;

#pragma unroll
    for (int s = 0; s < 4; ++s) {
        const half_t* S = (s == 0) ? A0 : (s == 1) ? P1 : (s == 2) ? P2 : P3;
        const float* Wsrc = W + s * IN * 64;
        for (int idx = t; idx < IN * 64; idx += 256) {
            int k = idx >> 6, colj = idx & 63;
            Wt[colj][k] = (_Float16)Wsrc[idx];
        }
        __syncthreads();
#pragma unroll
        for (int kk = 0; kk < KK; ++kk) {
            uint4 araw = *reinterpret_cast<const uint4*>(S + (size_t)row * IN + kk * 32 + khome);
            f16x8 afrag = __builtin_bit_cast(f16x8, araw);
#pragma unroll
            for (int ct = 0; ct < 4; ++ct) {
                f16x8 bfrag = *reinterpret_cast<const f16x8*>(&Wt[ct * 16 + (l & 15)][kk * 32 + khome]);
                acc[ct] = __builtin_amdgcn_mfma_f32_16x16x32_f16(afrag, bfrag, acc[ct], 0, 0, 0);
            }
        }
        __syncthreads();
    }

    int colb = l & 15;
    int rbase = rowTop + (l >> 4) * 4;
#pragma unroll
    for (int ct = 0; ct < 4; ++ct) {
#pragma unroll
        for (int r = 0; r < 4; ++r) {
            int node = rbase + r;
            if (node >= n) continue;
            int colj = ct * 16 + colb;
            float v = fmaxf(acc[ct][r] + bias[colj], 0.f);
            size_t o = (size_t)node * 64 + colj;
            if (MODE == 1) hdst[o] = __float2half_rn(v);
            else           fdst[o] = v;
        }
    }
}

// ---------------- host ----------------

extern "C" void kernel_launch(void* const* d_in, const int* in_sizes, int n_in,
                              void* d_out, int out_size, void* d_ws, size_t ws_size,
                              hipStream_t stream) {
    const float* x  = (const float*)d_in[0];
    const int*   ei = (const int*)d_in[1];
    const float* ew = (const float*)d_in[2];
    const float* W0 = (const float*)d_in[3];
    const float* b0 = (const float*)d_in[4];
    const float* Ws = (const float*)d_in[5];
    const float* bs = (const float*)d_in[6];
    float* out = (float*)d_out;

    const int* row = ei;
    const int* col = ei + NE;

    char* wsp = (char*)d_ws;
    auto alloc = [&](size_t bytes) -> char* {
        char* p = wsp;
        wsp += (bytes + 255) & ~(size_t)255;
        return p;
    };
    float*    dinv    = (float*)alloc((size_t)NCOL * 4);
    float*    deg     = (float*)alloc((size_t)NCOL * 4);
    unsigned* cnt     = (unsigned*)alloc((size_t)NCOL * 4);
    unsigned* offsets = (unsigned*)alloc((size_t)NCOL * 4);
    unsigned* bsum    = (unsigned*)alloc(256 * 4);
    unsigned* bbase   = (unsigned*)alloc(256 * 4);
    unsigned* gcur    = (unsigned*)alloc(NBKT * 4);
    int2*     ent     = (int2*)alloc((size_t)NE * 8);
    half_t*   xh      = (half_t*)alloc((size_t)NN * 32 * 2);
    half_t*   B0      = (half_t*)alloc((size_t)NN * 64 * 2);
    half_t*   P1      = (half_t*)alloc((size_t)NN * 64 * 2);
    half_t*   P2      = (half_t*)alloc((size_t)NN * 64 * 2);
    half_t*   P3      = (half_t*)alloc((size_t)NN * 64 * 2);
    // bucket staging aliases P1/P2 (first written after passC in stream order)
    int2*     gbkt    = (int2*)P1;   // 196*9216*8 = 14.45 MB < 25.6 MB (P1+P2)

    hipMemsetAsync(gcur, 0, NBKT * 4, stream);

    f32_to_f16<<<(NN * 32 / 4 + 255) / 256, 256, 0, stream>>>(x, xh, NN * 32 / 4);

    const int AB = (NE + EPB_A - 1) / EPB_A;   // 391
    passA_bucket<<<AB, 256, 0, stream>>>(row, col, ew, gcur, gbkt, NE);
    passB_hist<<<NBKT, 256, 0, stream>>>(gbkt, gcur, cnt, deg);
    dinv_kernel<<<(NN + 255) / 256, 256, 0, stream>>>(deg, dinv, NN);
    const int NB = NCOL / 1024;                // 98 exactly
    scan_phase1<<<NB, 256, 0, stream>>>(cnt, bsum, NCOL);
    scan_phase2<<<1, 128, 0, stream>>>(bsum, bbase, NB);
    scan_phase3<<<NB, 256, 0, stream>>>(cnt, bbase, offsets, NCOL);
    passC_place<<<NBKT, 256, 0, stream>>>(gbkt, gcur, offsets, dinv, ent);

    const int MMB = (NN + 63) / 64;            // 1563
    const int SB  = (NN + 31) / 32;            // 3125

    // ---- layer 0 (dim 32) ----
    spmm32_kernel<<<SB, 256, 0, stream>>>(xh, P1, ent, offsets, cnt, dinv, NN);
    spmm32_kernel<<<SB, 256, 0, stream>>>(P1, P2, ent, offsets, cnt, dinv, NN);
    spmm32_kernel<<<SB, 256, 0, stream>>>(P2, P3, ent, offsets, cnt, dinv, NN);
    fused4_mfma<32, 1><<<MMB, 256, 0, stream>>>(xh, P1, P2, P3, W0, b0, B0, nullptr, NN);

    // ---- layers 1..4 (dim 64) ----
    for (int l = 0; l < 4; ++l) {
        const float* Wl = Ws + (size_t)l * 4 * 64 * 64;
        const float* bl = bs + (size_t)l * 64;
        spmm64_kernel<<<SB, 256, 0, stream>>>(B0, P1, ent, offsets, cnt, dinv, NN);
        spmm64_kernel<<<SB, 256, 0, stream>>>(P1, P2, ent, offsets, cnt, dinv, NN);
        spmm64_kernel<<<SB, 256, 0, stream>>>(P2, P3, ent, offsets, cnt, dinv, NN);
        if (l < 3)
            fused4_mfma<64, 1><<<MMB, 256, 0, stream>>>(B0, P1, P2, P3, Wl, bl, B0, nullptr, NN);
        else
            fused4_mfma<64, 2><<<MMB, 256, 0, stream>>>(B0, P1, P2, P3, Wl, bl, nullptr, out, NN);
    }
}

// Round 10
// 633.053 us; speedup vs baseline: 1.1617x; 1.1617x over previous
//
#include <hip/hip_runtime.h>
#include <hip/hip_fp16.h>

#define NN 100000
#define NE 1600000
#define NBKT 196              // buckets of 512 cols: 99999>>9 = 195
#define BSH 9
#define BCAP 9216             // mean 8163 + 11.7 sigma
#define NCOL (NBKT * 512)     // 100352 = 98 * 1024 (scan-friendly)
#define EPB_A 4096

typedef __half half_t;
using f16x8 = __attribute__((ext_vector_type(8))) _Float16;
using f32x4 = __attribute__((ext_vector_type(4))) float;

// ---------------- helpers ----------------

__device__ inline float4 load4(const float* p) {
    return *reinterpret_cast<const float4*>(p);
}
__device__ inline float4 load4(const half_t* p) {
    uint2 u = *reinterpret_cast<const uint2*>(p);
    __half2 a = *reinterpret_cast<__half2*>(&u.x);
    __half2 b = *reinterpret_cast<__half2*>(&u.y);
    float2 fa = __half22float2(a), fb = __half22float2(b);
    return make_float4(fa.x, fa.y, fb.x, fb.y);
}
__device__ inline void store_half4(half_t* p, float4 v) {
    __half2 a = __floats2half2_rn(v.x, v.y);
    __half2 b = __floats2half2_rn(v.z, v.w);
    uint2 u;
    u.x = *reinterpret_cast<unsigned*>(&a);
    u.y = *reinterpret_cast<unsigned*>(&b);
    *reinterpret_cast<uint2*>(p) = u;
}
// decode packed edge: bits 31..15 = row, bits 14..0 = f16 weight (sign=0)
__device__ inline void edec(unsigned p, int& r, float& w) {
    r = (int)(p >> 15);
    unsigned short hb = (unsigned short)(p & 0x7FFFu);
    w = __half2float(*reinterpret_cast<__half*>(&hb));
}

// ---------------- setup: two-level bucket CSR build ----------------

__global__ void f32_to_f16(const float* __restrict__ in, half_t* __restrict__ out, int nquad) {
    int i = blockIdx.x * blockDim.x + threadIdx.x;
    if (i < nquad) store_half4(out + i * 4, load4(in + i * 4));
}

// passA: block-local counting sort by coarse bucket, sequential flush.
// packed = (col&511)<<17 | row   (row < 2^17)
__global__ __launch_bounds__(256) void passA_bucket(
    const int* __restrict__ row, const int* __restrict__ col, const float* __restrict__ w,
    unsigned* __restrict__ gcur, int2* __restrict__ gbkt, int E)
{
    __shared__ unsigned cnt[256];
    __shared__ unsigned lofs[256];
    __shared__ unsigned lcur[256];
    __shared__ unsigned gb[256];
    __shared__ int2 arena[EPB_A];
    __shared__ unsigned short abkt[EPB_A];
    int t = threadIdx.x;
    int base = blockIdx.x * EPB_A;
    int nloc = min(EPB_A, E - base);
    cnt[t] = 0; lcur[t] = 0;
    __syncthreads();
    for (int i = t; i < nloc; i += 256)
        atomicAdd(&cnt[col[base + i] >> BSH], 1u);
    __syncthreads();
    unsigned v = cnt[t];
    lofs[t] = v; __syncthreads();
    for (int d = 1; d < 256; d <<= 1) {
        unsigned u = (t >= d) ? lofs[t - d] : 0u;
        __syncthreads();
        lofs[t] += u;
        __syncthreads();
    }
    unsigned excl = lofs[t] - v;
    __syncthreads();
    lofs[t] = excl;
    __syncthreads();
    if (t < NBKT && cnt[t] > 0) gb[t] = atomicAdd(&gcur[t], cnt[t]);
    for (int i = t; i < nloc; i += 256) {
        int e = base + i;
        int c = col[e];
        int b = c >> BSH;
        unsigned p = lofs[b] + atomicAdd(&lcur[b], 1u);
        unsigned packed = ((unsigned)(c & 511) << 17) | (unsigned)row[e];
        arena[p] = make_int2((int)packed, __float_as_int(w[e]));
        abkt[p] = (unsigned short)b;
    }
    __syncthreads();
    for (int i = t; i < nloc; i += 256) {
        int b = abkt[i];
        unsigned j = i - lofs[b];
        gbkt[(size_t)b * BCAP + gb[b] + j] = arena[i];
    }
}

// passB: per-bucket 512-col histogram + weighted degree, sequential writes
__global__ __launch_bounds__(256) void passB_hist(
    const int2* __restrict__ gbkt, const unsigned* __restrict__ gcur,
    unsigned* __restrict__ cnt, float* __restrict__ deg)
{
    __shared__ unsigned c512[512];
    __shared__ float d512[512];
    int t = threadIdx.x;
    int b = blockIdx.x;
    for (int i = t; i < 512; i += 256) { c512[i] = 0; d512[i] = 0.f; }
    __syncthreads();
    unsigned sz = min(gcur[b], (unsigned)BCAP);
    const int2* src = gbkt + (size_t)b * BCAP;
    for (unsigned i = t; i < sz; i += 256) {
        int2 v = src[i];
        unsigned colw = ((unsigned)v.x) >> 17;
        atomicAdd(&c512[colw], 1u);
        atomicAdd(&d512[colw], __int_as_float(v.y));
    }
    __syncthreads();
    for (int i = t; i < 512; i += 256) {
        cnt[b * 512 + i] = c512[i];
        deg[b * 512 + i] = d512[i];
    }
}

__global__ void dinv_kernel(const float* __restrict__ deg, float* __restrict__ dinv, int n) {
    int i = blockIdx.x * blockDim.x + threadIdx.x;
    if (i < n) {
        float d = deg[i];
        dinv[i] = d > 0.f ? rsqrtf(d) : 0.f;
    }
}

__global__ void scan_phase1(const unsigned* __restrict__ cnt, unsigned* __restrict__ bsum, int n) {
    __shared__ unsigned sh[256];
    int t = threadIdx.x;
    int base = blockIdx.x * 1024 + t * 4;
    unsigned s = 0;
#pragma unroll
    for (int j = 0; j < 4; j++) { int i = base + j; if (i < n) s += cnt[i]; }
    sh[t] = s; __syncthreads();
    for (int d = 128; d > 0; d >>= 1) {
        if (t < d) sh[t] += sh[t + d];
        __syncthreads();
    }
    if (t == 0) bsum[blockIdx.x] = sh[0];
}

__global__ void scan_phase2(const unsigned* __restrict__ bsum, unsigned* __restrict__ bbase, int nb) {
    __shared__ unsigned sh[128];
    int t = threadIdx.x;
    unsigned v = (t < nb) ? bsum[t] : 0u;
    sh[t] = v; __syncthreads();
    for (int d = 1; d < 128; d <<= 1) {
        unsigned u = (t >= d) ? sh[t - d] : 0u;
        __syncthreads();
        sh[t] += u;
        __syncthreads();
    }
    if (t < nb) bbase[t] = sh[t] - v;   // exclusive
}

__global__ void scan_phase3(const unsigned* __restrict__ cnt, const unsigned* __restrict__ bbase,
                            unsigned* __restrict__ offsets, int n) {
    __shared__ unsigned sh[256];
    int t = threadIdx.x;
    int base = blockIdx.x * 1024 + t * 4;
    unsigned c[4]; unsigned s = 0;
#pragma unroll
    for (int j = 0; j < 4; j++) { int i = base + j; c[j] = (i < n) ? cnt[i] : 0u; s += c[j]; }
    sh[t] = s; __syncthreads();
    for (int d = 1; d < 256; d <<= 1) {
        unsigned u = (t >= d) ? sh[t - d] : 0u;
        __syncthreads();
        sh[t] += u;
        __syncthreads();
    }
    unsigned o = bbase[blockIdx.x] + sh[t] - s;
#pragma unroll
    for (int j = 0; j < 4; j++) {
        int i = base + j;
        if (i < n) { offsets[i] = o; o += c[j]; }
    }
}

// passC: per-bucket placement into final CSR (u32-packed); window ~32KB (L2-resident).
// ent[pos] = (row << 15) | f16bits(dinv[row]*w)   [weight >= 0 so sign bit is 0]
__global__ __launch_bounds__(256) void passC_place(
    const int2* __restrict__ gbkt, const unsigned* __restrict__ gcur,
    const unsigned* __restrict__ offsets, const float* __restrict__ dinv,
    unsigned* __restrict__ ent)
{
    __shared__ unsigned lcur[512];
    int t = threadIdx.x;
    int b = blockIdx.x;
    for (int i = t; i < 512; i += 256) lcur[i] = 0;
    __syncthreads();
    unsigned sz = min(gcur[b], (unsigned)BCAP);
    const int2* src = gbkt + (size_t)b * BCAP;
    for (unsigned i = t; i < sz; i += 256) {
        int2 v = src[i];
        unsigned colw = ((unsigned)v.x) >> 17;
        int r = v.x & 0x1FFFF;
        int c = (b << BSH) | (int)colw;
        unsigned pos = offsets[c] + atomicAdd(&lcur[colw], 1u);
        float wv = __int_as_float(v.y) * dinv[r];
        __half hh = __float2half_rn(wv);
        unsigned hb = *reinterpret_cast<unsigned short*>(&hh);
        ent[pos] = ((unsigned)r << 15) | hb;
    }
}

// ---------------- SpMM dim-32: 8 lanes/node, 8B lanes, u32 edges ----------------

__global__ __launch_bounds__(256) void spmm32_kernel(
    const half_t* __restrict__ src, half_t* __restrict__ pout,
    const unsigned* __restrict__ ent, const unsigned* __restrict__ offs,
    const unsigned* __restrict__ cnt, const float* __restrict__ dinv, int n)
{
    int node = blockIdx.x * 32 + (threadIdx.x >> 3);
    int f = (threadIdx.x & 7) * 4;
    if (node >= n) return;
    unsigned off = offs[node];
    unsigned c = cnt[node];
    float dv = dinv[node];
    float acc[4] = {};
#pragma unroll 2
    for (unsigned e = off; e < off + c; ++e) {
        int r; float w;
        edec(ent[e], r, w);
        uint2 raw = *reinterpret_cast<const uint2*>(src + (size_t)r * 32 + f);
        __half2* h2 = reinterpret_cast<__half2*>(&raw);
        float2 v0 = __half22float2(h2[0]), v1 = __half22float2(h2[1]);
        acc[0] += w * v0.x; acc[1] += w * v0.y;
        acc[2] += w * v1.x; acc[3] += w * v1.y;
    }
    uint2 o;
    __half2 h;
    h = __floats2half2_rn(acc[0] * dv, acc[1] * dv); o.x = *reinterpret_cast<unsigned*>(&h);
    h = __floats2half2_rn(acc[2] * dv, acc[3] * dv); o.y = *reinterpret_cast<unsigned*>(&h);
    *reinterpret_cast<uint2*>(pout + (size_t)node * 32 + f) = o;
}

// ---------------- SpMM dim-64: 8 lanes/node, 16B lanes, u32 edges ----------------

__global__ __launch_bounds__(256) void spmm64_kernel(
    const half_t* __restrict__ src, half_t* __restrict__ pout,
    const unsigned* __restrict__ ent, const unsigned* __restrict__ offs,
    const unsigned* __restrict__ cnt, const float* __restrict__ dinv, int n)
{
    int node = blockIdx.x * 32 + (threadIdx.x >> 3);
    int f = (threadIdx.x & 7) * 8;   // 8 halfs = 16B per lane
    if (node >= n) return;
    unsigned off = offs[node], c = cnt[node];
    float dv = dinv[node];
    float acc[8] = {};
#pragma unroll 2
    for (unsigned e = off; e < off + c; ++e) {
        int r; float w;
        edec(ent[e], r, w);
        uint4 raw = *reinterpret_cast<const uint4*>(src + (size_t)r * 64 + f);
        __half2* h2 = reinterpret_cast<__half2*>(&raw);
#pragma unroll
        for (int q = 0; q < 4; ++q) {
            float2 v = __half22float2(h2[q]);
            acc[2 * q]     += w * v.x;
            acc[2 * q + 1] += w * v.y;
        }
    }
    uint4 o;
    __half2 h;
    h = __floats2half2_rn(acc[0] * dv, acc[1] * dv); o.x = *reinterpret_cast<unsigned*>(&h);
    h = __floats2half2_rn(acc[2] * dv, acc[3] * dv); o.y = *reinterpret_cast<unsigned*>(&h);
    h = __floats2half2_rn(acc[4] * dv, acc[5] * dv); o.z = *reinterpret_cast<unsigned*>(&h);
    h = __floats2half2_rn(acc[6] * dv, acc[7] * dv); o.w = *reinterpret_cast<unsigned*>(&h);
    *reinterpret_cast<uint4*>(pout + (size_t)node * 64 + f) = o;
}

// ---------------- fused 4-source matmul via MFMA f16 ----------------

template <int IN, int MODE>
__global__ __launch_bounds__(256) void fused4_mfma(
    const half_t* __restrict__ A0, const half_t* __restrict__ P1,
    const half_t* __restrict__ P2, const half_t* __restrict__ P3,
    const float* __restrict__ W, const float* __restrict__ bias,
    half_t* __restrict__ hdst, float* __restrict__ fdst, int n)
{
    constexpr int KK  = IN / 32;
    constexpr int WTS = IN + 8;
    __shared__ _Float16 Wt[64][WTS];
    int t = threadIdx.x;
    int w = t >> 6, l = t & 63;
    int nodeBase = blockIdx.x * 64;
    int rowTop = nodeBase + w * 16;

    f32x4 acc[4];
#pragma unroll
    for (int ct = 0; ct < 4; ++ct) acc[ct] = (f32x4){0.f, 0.f, 0.f, 0.f};

    int row = rowTop + (l & 15);
    if (row >= n) row = n - 1;
    const int khome = (l >> 4) * 8;

#pragma unroll
    for (int s = 0; s < 4; ++s) {
        const half_t* S = (s == 0) ? A0 : (s == 1) ? P1 : (s == 2) ? P2 : P3;
        const float* Wsrc = W + s * IN * 64;
        for (int idx = t; idx < IN * 64; idx += 256) {
            int k = idx >> 6, colj = idx & 63;
            Wt[colj][k] = (_Float16)Wsrc[idx];
        }
        __syncthreads();
#pragma unroll
        for (int kk = 0; kk < KK; ++kk) {
            uint4 araw = *reinterpret_cast<const uint4*>(S + (size_t)row * IN + kk * 32 + khome);
            f16x8 afrag = __builtin_bit_cast(f16x8, araw);
#pragma unroll
            for (int ct = 0; ct < 4; ++ct) {
                f16x8 bfrag = *reinterpret_cast<const f16x8*>(&Wt[ct * 16 + (l & 15)][kk * 32 + khome]);
                acc[ct] = __builtin_amdgcn_mfma_f32_16x16x32_f16(afrag, bfrag, acc[ct], 0, 0, 0);
            }
        }
        __syncthreads();
    }

    int colb = l & 15;
    int rbase = rowTop + (l >> 4) * 4;
#pragma unroll
    for (int ct = 0; ct < 4; ++ct) {
#pragma unroll
        for (int r = 0; r < 4; ++r) {
            int node = rbase + r;
            if (node >= n) continue;
            int colj = ct * 16 + colb;
            float v = fmaxf(acc[ct][r] + bias[colj], 0.f);
            size_t o = (size_t)node * 64 + colj;
            if (MODE == 1) hdst[o] = __float2half_rn(v);
            else           fdst[o] = v;
        }
    }
}

// ---------------- host ----------------

extern "C" void kernel_launch(void* const* d_in, const int* in_sizes, int n_in,
                              void* d_out, int out_size, void* d_ws, size_t ws_size,
                              hipStream_t stream) {
    const float* x  = (const float*)d_in[0];
    const int*   ei = (const int*)d_in[1];
    const float* ew = (const float*)d_in[2];
    const float* W0 = (const float*)d_in[3];
    const float* b0 = (const float*)d_in[4];
    const float* Ws = (const float*)d_in[5];
    const float* bs = (const float*)d_in[6];
    float* out = (float*)d_out;

    const int* row = ei;
    const int* col = ei + NE;

    char* wsp = (char*)d_ws;
    auto alloc = [&](size_t bytes) -> char* {
        char* p = wsp;
        wsp += (bytes + 255) & ~(size_t)255;
        return p;
    };
    float*    dinv    = (float*)alloc((size_t)NCOL * 4);
    float*    deg     = (float*)alloc((size_t)NCOL * 4);
    unsigned* cnt     = (unsigned*)alloc((size_t)NCOL * 4);
    unsigned* offsets = (unsigned*)alloc((size_t)NCOL * 4);
    unsigned* bsum    = (unsigned*)alloc(256 * 4);
    unsigned* bbase   = (unsigned*)alloc(256 * 4);
    unsigned* gcur    = (unsigned*)alloc(NBKT * 4);
    unsigned* ent     = (unsigned*)alloc((size_t)NE * 4);   // u32-packed edges
    half_t*   xh      = (half_t*)alloc((size_t)NN * 32 * 2);
    half_t*   B0      = (half_t*)alloc((size_t)NN * 64 * 2);
    half_t*   P1      = (half_t*)alloc((size_t)NN * 64 * 2);
    half_t*   P2      = (half_t*)alloc((size_t)NN * 64 * 2);
    half_t*   P3      = (half_t*)alloc((size_t)NN * 64 * 2);
    // bucket staging aliases P1/P2 (first written after passC in stream order)
    int2*     gbkt    = (int2*)P1;   // 196*9216*8 = 14.45 MB < 25.6 MB (P1+P2)

    hipMemsetAsync(gcur, 0, NBKT * 4, stream);

    f32_to_f16<<<(NN * 32 / 4 + 255) / 256, 256, 0, stream>>>(x, xh, NN * 32 / 4);

    const int AB = (NE + EPB_A - 1) / EPB_A;   // 391
    passA_bucket<<<AB, 256, 0, stream>>>(row, col, ew, gcur, gbkt, NE);
    passB_hist<<<NBKT, 256, 0, stream>>>(gbkt, gcur, cnt, deg);
    dinv_kernel<<<(NN + 255) / 256, 256, 0, stream>>>(deg, dinv, NN);
    const int NB = NCOL / 1024;                // 98 exactly
    scan_phase1<<<NB, 256, 0, stream>>>(cnt, bsum, NCOL);
    scan_phase2<<<1, 128, 0, stream>>>(bsum, bbase, NB);
    scan_phase3<<<NB, 256, 0, stream>>>(cnt, bbase, offsets, NCOL);
    passC_place<<<NBKT, 256, 0, stream>>>(gbkt, gcur, offsets, dinv, ent);

    const int MMB = (NN + 63) / 64;            // 1563
    const int SB  = (NN + 31) / 32;            // 3125

    // ---- layer 0 (dim 32) ----
    spmm32_kernel<<<SB, 256, 0, stream>>>(xh, P1, ent, offsets, cnt, dinv, NN);
    spmm32_kernel<<<SB, 256, 0, stream>>>(P1, P2, ent, offsets, cnt, dinv, NN);
    spmm32_kernel<<<SB, 256, 0, stream>>>(P2, P3, ent, offsets, cnt, dinv, NN);
    fused4_mfma<32, 1><<<MMB, 256, 0, stream>>>(xh, P1, P2, P3, W0, b0, B0, nullptr, NN);

    // ---- layers 1..4 (dim 64) ----
    for (int l = 0; l < 4; ++l) {
        const float* Wl = Ws + (size_t)l * 4 * 64 * 64;
        const float* bl = bs + (size_t)l * 64;
        spmm64_kernel<<<SB, 256, 0, stream>>>(B0, P1, ent, offsets, cnt, dinv, NN);
        spmm64_kernel<<<SB, 256, 0, stream>>>(P1, P2, ent, offsets, cnt, dinv, NN);
        spmm64_kernel<<<SB, 256, 0, stream>>>(P2, P3, ent, offsets, cnt, dinv, NN);
        if (l < 3)
            fused4_mfma<64, 1><<<MMB, 256, 0, stream>>>(B0, P1, P2, P3, Wl, bl, B0, nullptr, NN);
        else
            fused4_mfma<64, 2><<<MMB, 256, 0, stream>>>(B0, P1, P2, P3, Wl, bl, nullptr, out, NN);
    }
}